// Round 8
// baseline (2069.370 us; speedup 1.0000x reference)
//
#include <hip/hip_runtime.h>
#include <math.h>

#define N_MEM 100
#define C_DIM 768
#define HW_SZ 2304            // 48*48
#define TEMP 0.07f
#define EPS_F 1e-8f
#define LAM_F 0.01f           // 1/N_MEM
#define NORM_EPS 1e-12f

#define NS   4                // n-split stripes in mTp layout (fixed)
#define SW   25               // stripe width (N_MEM/NS)
#define SWP  28               // padded stripe (16B-aligned for s_load_dwordx4)
#define ROWS 64               // rows per scores-block
#define SCP  101              // LDS row pad: stride%32=5, coprime -> 2-way max
#define CB   24               // recon c-tile per register block
#define ZB   16               // scores c-loop batch: 16 z-loads in flight [R8]
#define RROWS 128             // recon rows per block (2 per thread)      [R8]

// -------------------------------------------------------------------------
// Kernel 1: L2-normalize memory rows, store PADDED-TRANSPOSED:
// mTp[c][ns][SWP]. Same value bits as R1's mT (same reduction).
// -------------------------------------------------------------------------
__global__ __launch_bounds__(64) void prep_mT(const float* __restrict__ mem,
                                              float* __restrict__ mTp) {
#pragma clang fp contract(off)
    const int n = blockIdx.x;        // 0..99
    const int lane = threadIdx.x;    // 0..63
    const float* row = mem + n * C_DIM;

    float ss = 0.f;
    for (int c = lane; c < C_DIM; c += 64) {
        float v = row[c];
        ss = fmaf(v, v, ss);
    }
    for (int off = 32; off > 0; off >>= 1)
        ss += __shfl_down(ss, off);
    float norm = sqrtf(__shfl(ss, 0));
    float inv = 1.0f / fmaxf(norm, NORM_EPS);

    const int nsI = n / SW, j = n % SW;
    for (int c = lane; c < C_DIM; c += 64)
        mTp[(size_t)c * (NS * SWP) + nsI * SWP + j] = row[c] * inv;
}

// -------------------------------------------------------------------------
// Kernel 2: scores + softmax + shrinkage + renorm -> writes w_hat (What).
// R8 change: ZB 8 -> 16 (deeper VMEM batch; FMA c-order unchanged ->
// bit-identical, absmax 4.94e-3 vs threshold 5.27e-3 across R1/R5/R6/R7).
// -------------------------------------------------------------------------
__global__ __launch_bounds__(256) void memmod_scores(const float* __restrict__ F,
                                                     const float* __restrict__ mTp,
                                                     float* __restrict__ What) {
#pragma clang fp contract(off)
    __shared__ float sc[ROWS][SCP];

    const int tid  = threadIdx.x;
    const int lane = tid & 63;
    const int ws   = tid >> 6;
    const int wsu  = __builtin_amdgcn_readfirstlane(ws);   // force SGPR addr
    const int blk  = blockIdx.x;                 // 0..2303
    const int b    = blk / 36;                   // 36 blocks per image
    const int hw   = (blk % 36) * 64 + lane;     // 0..2303
    const int rowg = b * HW_SZ + hw;             // global row id
    const size_t plane = (size_t)b * C_DIM * HW_SZ + hw;

    float acc[SW];
#pragma unroll
    for (int j = 0; j < SW; ++j) acc[j] = 0.f;
    float ss = 0.f;

    // ---- scores: 16 batched loads, sequential-c FMA chains ----
    const float* Fp = F + plane;
    for (int c0 = 0; c0 < C_DIM; c0 += ZB) {
        float zb[ZB];                            // static indices -> VGPRs
#pragma unroll
        for (int u = 0; u < ZB; ++u)
            zb[u] = Fp[(size_t)(c0 + u) * HW_SZ];    // 16 coalesced loads in flight
#pragma unroll
        for (int u = 0; u < ZB; ++u) {
            const float zc = zb[u];
            ss = fmaf(zc, zc, ss);
            const float* mch = mTp + (size_t)(c0 + u) * (NS * SWP) + wsu * SWP;
#pragma unroll
            for (int j = 0; j < SW; ++j)
                acc[j] = fmaf(zc, mch[j], acc[j]);
        }
    }

    // ---- stage scores to LDS (read-only afterwards -> race-free) ----
#pragma unroll
    for (int j = 0; j < SW; ++j)
        sc[lane][wsu * SW + j] = acc[j];
    __syncthreads();

    // ---- softmax + shrinkage: R1's exact op sequence, n = 0..99 ----
    const float scale = 1.0f / (fmaxf(sqrtf(ss), NORM_EPS) * TEMP);
    float mx = -INFINITY;
    for (int n = 0; n < N_MEM; ++n)
        mx = fmaxf(mx, sc[lane][n] * scale);
    float sum = 0.f;
    for (int n = 0; n < N_MEM; ++n)
        sum += expf(sc[lane][n] * scale - mx);
    float s2 = 0.f;
    for (int n = 0; n < N_MEM; ++n) {
        const float e = expf(sc[lane][n] * scale - mx);   // same bits as pass 2
        const float w = e / sum;
        const float d = w - LAM_F;
        s2 += (d > 0.f ? d : 0.f) * w / (fabsf(d) + EPS_F);
    }
    const float s2c = fmaxf(s2, EPS_F);

    // ---- own stripe: recompute wh from registers (same bits), emit ----
    float* wout = What + (size_t)rowg * N_MEM + wsu * SW;
#pragma unroll
    for (int j = 0; j < SW; ++j) {
        const float e = expf(acc[j] * scale - mx);
        const float w = e / sum;
        const float d = w - LAM_F;
        const float wh = (d > 0.f ? d : 0.f) * w / (fabsf(d) + EPS_F);
        wout[j] = wh / s2c;
    }
}

// -------------------------------------------------------------------------
// Kernel 3: reconstruction  Fhat[b][c][hw] = sum_n w_hat[row][n]*m[n][c].
// R8 change: back to 4 waves (R6 shape beat R7's 8-wave) + TWO rows per
// thread (rows lane and lane+64 of a 128-row block): each s_load'd mch[j]
// feeds 2 FMAs -> SMEM-per-FMA halves, per-stall work doubles. Per-output
// n-order (nc 0..3, j 0..24 ascending) unchanged -> bit-identical.
// LDS 51.7KB -> 3 blocks/CU; VGPR ~120; NO occupancy floor (R3 lesson).
// -------------------------------------------------------------------------
__global__ __launch_bounds__(256) void memmod_recon(const float* __restrict__ What,
                                                    const float* __restrict__ mTp,
                                                    float* __restrict__ Fhat) {
#pragma clang fp contract(off)
    __shared__ float wh[RROWS][SCP];

    const int tid  = threadIdx.x;                // 0..255
    const int lane = tid & 63;
    const int ws   = tid >> 6;                   // 0..3
    const int wsu  = __builtin_amdgcn_readfirstlane(ws);
    const int blk  = blockIdx.x;                 // 0..1151
    const int b    = blk / 18;                   // 18 blocks per image
    const int h0   = (blk % 18) * RROWS;
    const int hw0  = h0 + lane;                  // row A
    const int hw1  = h0 + 64 + lane;             // row B

    // ---- stage 128 rows x 100 w_hat into LDS (coalesced float4 reads) ----
    const float4* src4 =
        reinterpret_cast<const float4*>(What + ((size_t)b * HW_SZ + h0) * N_MEM);
    for (int i = tid; i < RROWS * N_MEM / 4; i += 256) {
        const float4 v = src4[i];
        const int f = i * 4, r = f / N_MEM, n = f % N_MEM;
        wh[r][n] = v.x; wh[r][n + 1] = v.y; wh[r][n + 2] = v.z; wh[r][n + 3] = v.w;
    }
    __syncthreads();

    const size_t base = (size_t)b * C_DIM * HW_SZ;
    float* Fo0 = Fhat + base + hw0;
    float* Fo1 = Fhat + base + hw1;
    const int c0w = wsu * (C_DIM / NS);          // 192-wide c-stripe

    for (int cb = 0; cb < C_DIM / NS; cb += CB) {
        float v0[CB], v1[CB];
#pragma unroll
        for (int t = 0; t < CB; ++t) { v0[t] = 0.f; v1[t] = 0.f; }

#pragma unroll
        for (int nc = 0; nc < NS; ++nc) {
            float wr0[SW], wr1[SW];
#pragma unroll
            for (int j = 0; j < SW; ++j) {
                wr0[j] = wh[lane][nc * SW + j];        // 2-way max (stride 101)
                wr1[j] = wh[64 + lane][nc * SW + j];
            }
#pragma unroll
            for (int t = 0; t < CB; ++t) {
                const float* mch =
                    mTp + (size_t)(c0w + cb + t) * (NS * SWP) + nc * SWP; // s_load
#pragma unroll
                for (int j = 0; j < SW; ++j) {
                    const float mv = mch[j];           // loaded once, used 2x
                    v0[t] = fmaf(wr0[j], mv, v0[t]);   // n ascending overall
                    v1[t] = fmaf(wr1[j], mv, v1[t]);
                }
            }
        }
#pragma unroll
        for (int t = 0; t < CB; ++t) {
            Fo0[(size_t)(c0w + cb + t) * HW_SZ] = v0[t];  // coalesced per c
            Fo1[(size_t)(c0w + cb + t) * HW_SZ] = v1[t];
        }
    }
}

// -------------------------------------------------------------------------
extern "C" void kernel_launch(void* const* d_in, const int* in_sizes, int n_in,
                              void* d_out, int out_size, void* d_ws, size_t ws_size,
                              hipStream_t stream) {
    const float* F   = (const float*)d_in[0];   // [64,768,48,48]
    const float* mem = (const float*)d_in[1];   // [100,768]
    float* Fhat = (float*)d_out;                               // 113,246,208 floats
    float* What = (float*)d_out + (size_t)64 * 768 * 48 * 48;  // 14,745,600 floats
    float* mTp  = (float*)d_ws;                                // 768*4*28 floats

    prep_mT<<<N_MEM, 64, 0, stream>>>(mem, mTp);
    memmod_scores<<<2304, 256, 0, stream>>>(F, mTp, What);
    memmod_recon<<<1152, 256, 0, stream>>>(What, mTp, Fhat);
}

// Round 9
// 1127.177 us; speedup vs baseline: 1.8359x; 1.8359x over previous
//
#include <hip/hip_runtime.h>
#include <math.h>

#define N_MEM 100
#define C_DIM 768
#define HW_SZ 2304            // 48*48
#define TEMP 0.07f
#define EPS_F 1e-8f
#define LAM_F 0.01f           // 1/N_MEM
#define NORM_EPS 1e-12f

#define NS   4                // n-split stripes in mTp layout (fixed)
#define SW   25               // stripe width (N_MEM/NS)
#define SWP  28               // padded stripe (112B: 16B-aligned stripes)
#define CROW (NS * SWP)       // 112 floats per c in mTp
#define ROWS 64               // rows per block (both kernels)
#define SCP  101              // LDS row pad: lane*101%32=lane*5 -> 2-way max
#define ZB   8                // scores c-loop batch (R6 value; 16 gave nothing)
#define CH_S 64               // scores m-chunk c's  (28672B, union'd with sc)
#define CB_R 8                // recon c-tile per stage per wave

// -------------------------------------------------------------------------
// Kernel 1: L2-normalize memory rows, store PADDED-TRANSPOSED:
// mTp[c][ns][SWP]. Same value bits as R1's mT (same reduction).
// -------------------------------------------------------------------------
__global__ __launch_bounds__(64) void prep_mT(const float* __restrict__ mem,
                                              float* __restrict__ mTp) {
#pragma clang fp contract(off)
    const int n = blockIdx.x;        // 0..99
    const int lane = threadIdx.x;    // 0..63
    const float* row = mem + n * C_DIM;

    float ss = 0.f;
    for (int c = lane; c < C_DIM; c += 64) {
        float v = row[c];
        ss = fmaf(v, v, ss);
    }
    for (int off = 32; off > 0; off >>= 1)
        ss += __shfl_down(ss, off);
    float norm = sqrtf(__shfl(ss, 0));
    float inv = 1.0f / fmaxf(norm, NORM_EPS);

    const int nsI = n / SW, j = n % SW;
    for (int c = lane; c < C_DIM; c += 64)
        mTp[(size_t)c * CROW + nsI * SWP + j] = row[c] * inv;
}

// -------------------------------------------------------------------------
// Kernel 2: scores + softmax + shrinkage + renorm -> writes w_hat (What).
// R9 change: m comes from LDS (staged 64-c chunks, broadcast reads) instead
// of s_load — removes the SMEM serial chain both kernels plateaued on.
// The m-chunk buffer is UNION'd with the sc buffer (used only after the
// main loop) -> 28.7KB LDS -> 5 blocks/CU = 20 waves/CU (was ~11).
// FMA c-order and softmax sequence unchanged -> bit-identical
// (absmax 4.94e-3 vs threshold 5.27e-3, stable R1/R5-R8).
// -------------------------------------------------------------------------
__global__ __launch_bounds__(256) void memmod_scores(const float* __restrict__ F,
                                                     const float* __restrict__ mTp,
                                                     float* __restrict__ What) {
#pragma clang fp contract(off)
    __shared__ float u[CH_S * CROW];             // 7168 floats = 28672 B
    float* mbuf = u;                             // phase 1: [CH_S][112]
    float* scb  = u;                             // phase 2: [ROWS][SCP]

    const int tid  = threadIdx.x;
    const int lane = tid & 63;
    const int ws   = tid >> 6;
    const int wsu  = __builtin_amdgcn_readfirstlane(ws);
    const int blk  = blockIdx.x;                 // 0..2303
    const int b    = blk / 36;                   // 36 blocks per image
    const int hw   = (blk % 36) * 64 + lane;     // 0..2303
    const int rowg = b * HW_SZ + hw;             // global row id
    const size_t plane = (size_t)b * C_DIM * HW_SZ + hw;

    float acc[SW];
#pragma unroll
    for (int j = 0; j < SW; ++j) acc[j] = 0.f;
    float ss = 0.f;

    const float* Fp = F + plane;
    for (int c0 = 0; c0 < C_DIM; c0 += CH_S) {
        __syncthreads();                         // prior chunk fully consumed
        {   // stage 64 c's of mTp: contiguous 7168 floats, coalesced float4
            const float4* src4 = reinterpret_cast<const float4*>(mTp + (size_t)c0 * CROW);
            float4* dst4 = reinterpret_cast<float4*>(mbuf);
            for (int i = tid; i < CH_S * CROW / 4; i += 256)
                dst4[i] = src4[i];
        }
        __syncthreads();

        for (int cb = 0; cb < CH_S; cb += ZB) {
            float zb[ZB];                        // static indices -> VGPRs
#pragma unroll
            for (int uu = 0; uu < ZB; ++uu)
                zb[uu] = Fp[(size_t)(c0 + cb + uu) * HW_SZ];   // coalesced, 8 in flight
#pragma unroll
            for (int uu = 0; uu < ZB; ++uu) {
                const float zc = zb[uu];
                ss = fmaf(zc, zc, ss);
                const float* mch = mbuf + (cb + uu) * CROW + wsu * SWP;  // LDS broadcast
#pragma unroll
                for (int j = 0; j < SW; ++j)
                    acc[j] = fmaf(zc, mch[j], acc[j]);
            }
        }
    }

    // ---- phase 2: reuse LDS as sc[ROWS][SCP] (all mbuf reads done) ----
    __syncthreads();
#pragma unroll
    for (int j = 0; j < SW; ++j)
        scb[lane * SCP + wsu * SW + j] = acc[j];
    __syncthreads();

    // ---- softmax + shrinkage: R1's exact op sequence, n = 0..99 ----
    const float scale = 1.0f / (fmaxf(sqrtf(ss), NORM_EPS) * TEMP);
    float mx = -INFINITY;
    for (int n = 0; n < N_MEM; ++n)
        mx = fmaxf(mx, scb[lane * SCP + n] * scale);
    float sum = 0.f;
    for (int n = 0; n < N_MEM; ++n)
        sum += expf(scb[lane * SCP + n] * scale - mx);
    float s2 = 0.f;
    for (int n = 0; n < N_MEM; ++n) {
        const float e = expf(scb[lane * SCP + n] * scale - mx);
        const float w = e / sum;
        const float d = w - LAM_F;
        s2 += (d > 0.f ? d : 0.f) * w / (fabsf(d) + EPS_F);
    }
    const float s2c = fmaxf(s2, EPS_F);

    // ---- own stripe: recompute wh from registers (same bits), emit ----
    float* wout = What + (size_t)rowg * N_MEM + wsu * SW;
#pragma unroll
    for (int j = 0; j < SW; ++j) {
        const float e = expf(acc[j] * scale - mx);
        const float w = e / sum;
        const float d = w - LAM_F;
        const float wh = (d > 0.f ? d : 0.f) * w / (fabsf(d) + EPS_F);
        wout[j] = wh / s2c;
    }
}

// -------------------------------------------------------------------------
// Kernel 3: reconstruction  Fhat[b][c][hw] = sum_n w_hat[row][n]*m[n][c].
// EXACT R6 structure (best recon: 675us) with ONE change: mch comes from a
// staged LDS chunk ([4 stripes][CB_R=8 c][112] = 14.3KB) instead of s_load.
// Total LDS 40.2KB -> 4 blocks/CU = 16 waves/CU (was ~11). Per-output
// n-order (nc 0..3, j 0..24 ascending) unchanged -> bit-identical.
// -------------------------------------------------------------------------
__global__ __launch_bounds__(256) void memmod_recon(const float* __restrict__ What,
                                                    const float* __restrict__ mTp,
                                                    float* __restrict__ Fhat) {
#pragma clang fp contract(off)
    __shared__ float wh[ROWS][SCP];              // 25856 B
    __shared__ float mbuf[NS * CB_R * CROW];     // 4*8*112 floats = 14336 B

    const int tid  = threadIdx.x;                // 0..255
    const int lane = tid & 63;
    const int ws   = tid >> 6;                   // 0..3
    const int wsu  = __builtin_amdgcn_readfirstlane(ws);
    const int blk  = blockIdx.x;                 // 0..2303
    const int b    = blk / 36;
    const int h0   = (blk % 36) * 64;
    const int hw   = h0 + lane;

    // ---- stage 64 rows x 100 w_hat into LDS (coalesced float4 reads) ----
    {
        const float4* src4 =
            reinterpret_cast<const float4*>(What + ((size_t)b * HW_SZ + h0) * N_MEM);
        for (int i = tid; i < ROWS * N_MEM / 4; i += 256) {
            const float4 v = src4[i];
            const int f = i * 4, r = f / N_MEM, n = f % N_MEM;
            wh[r][n] = v.x; wh[r][n + 1] = v.y; wh[r][n + 2] = v.z; wh[r][n + 3] = v.w;
        }
    }

    const size_t plane = (size_t)b * C_DIM * HW_SZ + hw;
    float* Fo = Fhat + plane;
    const int c0w = wsu * (C_DIM / NS);          // 192-wide c-stripe

    for (int cb = 0; cb < C_DIM / NS; cb += CB_R) {
        __syncthreads();                         // prior chunk consumed (also covers wh)
        {   // stage 4 stripes x CB_R c's x 112 floats = 896 float4
            float4* dst4 = reinterpret_cast<float4*>(mbuf);
            for (int i = tid; i < NS * CB_R * CROW / 4; i += 256) {
                const int s   = i / (CB_R * CROW / 4);
                const int rem = i % (CB_R * CROW / 4);
                const float4* src4 = reinterpret_cast<const float4*>(
                    mTp + (size_t)(s * (C_DIM / NS) + cb) * CROW);
                dst4[i] = src4[rem];
            }
        }
        __syncthreads();

        float v[CB_R];
#pragma unroll
        for (int t = 0; t < CB_R; ++t) v[t] = 0.f;

#pragma unroll
        for (int nc = 0; nc < NS; ++nc) {
            float wr[SW];
#pragma unroll
            for (int j = 0; j < SW; ++j)
                wr[j] = wh[lane][nc * SW + j];    // stride 101 -> 2-way max
#pragma unroll
            for (int t = 0; t < CB_R; ++t) {
                const float* mch = mbuf + (wsu * CB_R + t) * CROW + nc * SWP; // broadcast
#pragma unroll
                for (int j = 0; j < SW; ++j)
                    v[t] = fmaf(wr[j], mch[j], v[t]);   // n ascending overall
            }
        }
#pragma unroll
        for (int t = 0; t < CB_R; ++t)
            Fo[(size_t)(c0w + cb + t) * HW_SZ] = v[t];  // coalesced per c
    }
}

// -------------------------------------------------------------------------
extern "C" void kernel_launch(void* const* d_in, const int* in_sizes, int n_in,
                              void* d_out, int out_size, void* d_ws, size_t ws_size,
                              hipStream_t stream) {
    const float* F   = (const float*)d_in[0];   // [64,768,48,48]
    const float* mem = (const float*)d_in[1];   // [100,768]
    float* Fhat = (float*)d_out;                               // 113,246,208 floats
    float* What = (float*)d_out + (size_t)64 * 768 * 48 * 48;  // 14,745,600 floats
    float* mTp  = (float*)d_ws;                                // 768*112 floats

    prep_mT<<<N_MEM, 64, 0, stream>>>(mem, mTp);
    memmod_scores<<<2304, 256, 0, stream>>>(F, mTp, What);
    memmod_recon<<<2304, 256, 0, stream>>>(What, mTp, Fhat);
}

// Round 10
// 1095.702 us; speedup vs baseline: 1.8886x; 1.0287x over previous
//
#include <hip/hip_runtime.h>
#include <math.h>

#define N_MEM 100
#define C_DIM 768
#define HW_SZ 2304            // 48*48
#define TEMP 0.07f
#define EPS_F 1e-8f
#define LAM_F 0.01f           // 1/N_MEM
#define NORM_EPS 1e-12f

#define NS   4                // n-split stripes in mTp layout (fixed)
#define SW   25               // stripe width (N_MEM/NS)
#define SWP  28               // padded stripe (112B: 16B-aligned stripes)
#define CROW (NS * SWP)       // 112 floats per c in mTp
#define ROWS 64               // rows per block (both kernels)
#define SCP  101              // LDS row pad: lane*101%32=lane*5 -> 2-way max
#define ZB   8                // scores c-loop batch
#define CB_R 8                // recon c-tile per stage per wave

// -------------------------------------------------------------------------
// Kernel 1: L2-normalize memory rows, store PADDED-TRANSPOSED:
// mTp[c][ns][SWP]. Same value bits as R1's mT (same reduction).
// -------------------------------------------------------------------------
__global__ __launch_bounds__(64) void prep_mT(const float* __restrict__ mem,
                                              float* __restrict__ mTp) {
#pragma clang fp contract(off)
    const int n = blockIdx.x;        // 0..99
    const int lane = threadIdx.x;    // 0..63
    const float* row = mem + n * C_DIM;

    float ss = 0.f;
    for (int c = lane; c < C_DIM; c += 64) {
        float v = row[c];
        ss = fmaf(v, v, ss);
    }
    for (int off = 32; off > 0; off >>= 1)
        ss += __shfl_down(ss, off);
    float norm = sqrtf(__shfl(ss, 0));
    float inv = 1.0f / fmaxf(norm, NORM_EPS);

    const int nsI = n / SW, j = n % SW;
    for (int c = lane; c < C_DIM; c += 64)
        mTp[(size_t)c * CROW + nsI * SWP + j] = row[c] * inv;
}

// -------------------------------------------------------------------------
// Kernel 2: scores + softmax + shrinkage + renorm -> writes w_hat (What).
// R10: reverted to the R6 s_load form (fastest scores: ~600us). R9's LDS
// broadcast moved ~50GB through LDS (1024B/inst for 16B unique) and was
// SLOWER (720us). Wave-uniform operands belong in the scalar K$.
// FMA c-order and softmax sequence unchanged -> bit-identical
// (absmax 4.94e-3 vs threshold 5.27e-3, stable across R1/R5-R9).
// -------------------------------------------------------------------------
__global__ __launch_bounds__(256) void memmod_scores(const float* __restrict__ F,
                                                     const float* __restrict__ mTp,
                                                     float* __restrict__ What) {
#pragma clang fp contract(off)
    __shared__ float sc[ROWS][SCP];

    const int tid  = threadIdx.x;
    const int lane = tid & 63;
    const int ws   = tid >> 6;
    const int wsu  = __builtin_amdgcn_readfirstlane(ws);   // force SGPR addr
    const int blk  = blockIdx.x;                 // 0..2303
    const int b    = blk / 36;                   // 36 blocks per image
    const int hw   = (blk % 36) * 64 + lane;     // 0..2303
    const int rowg = b * HW_SZ + hw;             // global row id
    const size_t plane = (size_t)b * C_DIM * HW_SZ + hw;

    float acc[SW];
#pragma unroll
    for (int j = 0; j < SW; ++j) acc[j] = 0.f;
    float ss = 0.f;

    // ---- scores: batched z loads, sequential-c FMA chains, s_load m ----
    const float* Fp = F + plane;
    for (int c0 = 0; c0 < C_DIM; c0 += ZB) {
        float zb[ZB];                            // static indices -> VGPRs
#pragma unroll
        for (int u = 0; u < ZB; ++u)
            zb[u] = Fp[(size_t)(c0 + u) * HW_SZ];    // 8 coalesced loads in flight
#pragma unroll
        for (int u = 0; u < ZB; ++u) {
            const float zc = zb[u];
            ss = fmaf(zc, zc, ss);
            const float* mch = mTp + (size_t)(c0 + u) * CROW + wsu * SWP;  // s_load
#pragma unroll
            for (int j = 0; j < SW; ++j)
                acc[j] = fmaf(zc, mch[j], acc[j]);
        }
    }

    // ---- stage scores to LDS (read-only afterwards -> race-free) ----
#pragma unroll
    for (int j = 0; j < SW; ++j)
        sc[lane][wsu * SW + j] = acc[j];
    __syncthreads();

    // ---- softmax + shrinkage: R1's exact op sequence, n = 0..99 ----
    const float scale = 1.0f / (fmaxf(sqrtf(ss), NORM_EPS) * TEMP);
    float mx = -INFINITY;
    for (int n = 0; n < N_MEM; ++n)
        mx = fmaxf(mx, sc[lane][n] * scale);
    float sum = 0.f;
    for (int n = 0; n < N_MEM; ++n)
        sum += expf(sc[lane][n] * scale - mx);
    float s2 = 0.f;
    for (int n = 0; n < N_MEM; ++n) {
        const float e = expf(sc[lane][n] * scale - mx);   // same bits as pass 2
        const float w = e / sum;
        const float d = w - LAM_F;
        s2 += (d > 0.f ? d : 0.f) * w / (fabsf(d) + EPS_F);
    }
    const float s2c = fmaxf(s2, EPS_F);

    // ---- own stripe: recompute wh from registers (same bits), emit ----
    float* wout = What + (size_t)rowg * N_MEM + wsu * SW;
#pragma unroll
    for (int j = 0; j < SW; ++j) {
        const float e = expf(acc[j] * scale - mx);
        const float w = e / sum;
        const float d = w - LAM_F;
        const float wh = (d > 0.f ? d : 0.f) * w / (fabsf(d) + EPS_F);
        wout[j] = wh / s2c;
    }
}

// -------------------------------------------------------------------------
// Kernel 3: reconstruction  Fhat[b][c][hw] = sum_n w_hat[row][n]*m[n][c].
// UNCHANGED from R9 (best recon: ~380us). LDS-staged m (broadcast) beats
// the serialized 150-load SMEM chain here. Per-output n-order (nc 0..3,
// j 0..24 ascending) unchanged -> bit-identical.
// -------------------------------------------------------------------------
__global__ __launch_bounds__(256) void memmod_recon(const float* __restrict__ What,
                                                    const float* __restrict__ mTp,
                                                    float* __restrict__ Fhat) {
#pragma clang fp contract(off)
    __shared__ float wh[ROWS][SCP];              // 25856 B
    __shared__ float mbuf[NS * CB_R * CROW];     // 4*8*112 floats = 14336 B

    const int tid  = threadIdx.x;                // 0..255
    const int lane = tid & 63;
    const int ws   = tid >> 6;                   // 0..3
    const int wsu  = __builtin_amdgcn_readfirstlane(ws);
    const int blk  = blockIdx.x;                 // 0..2303
    const int b    = blk / 36;
    const int h0   = (blk % 36) * 64;
    const int hw   = h0 + lane;

    // ---- stage 64 rows x 100 w_hat into LDS (coalesced float4 reads) ----
    {
        const float4* src4 =
            reinterpret_cast<const float4*>(What + ((size_t)b * HW_SZ + h0) * N_MEM);
        for (int i = tid; i < ROWS * N_MEM / 4; i += 256) {
            const float4 v = src4[i];
            const int f = i * 4, r = f / N_MEM, n = f % N_MEM;
            wh[r][n] = v.x; wh[r][n + 1] = v.y; wh[r][n + 2] = v.z; wh[r][n + 3] = v.w;
        }
    }

    const size_t plane = (size_t)b * C_DIM * HW_SZ + hw;
    float* Fo = Fhat + plane;
    const int c0w = wsu * (C_DIM / NS);          // 192-wide c-stripe

    for (int cb = 0; cb < C_DIM / NS; cb += CB_R) {
        __syncthreads();                         // prior chunk consumed (also covers wh)
        {   // stage 4 stripes x CB_R c's x 112 floats = 896 float4
            float4* dst4 = reinterpret_cast<float4*>(mbuf);
            for (int i = tid; i < NS * CB_R * CROW / 4; i += 256) {
                const int s   = i / (CB_R * CROW / 4);
                const int rem = i % (CB_R * CROW / 4);
                const float4* src4 = reinterpret_cast<const float4*>(
                    mTp + (size_t)(s * (C_DIM / NS) + cb) * CROW);
                dst4[i] = src4[rem];
            }
        }
        __syncthreads();

        float v[CB_R];
#pragma unroll
        for (int t = 0; t < CB_R; ++t) v[t] = 0.f;

#pragma unroll
        for (int nc = 0; nc < NS; ++nc) {
            float wr[SW];
#pragma unroll
            for (int j = 0; j < SW; ++j)
                wr[j] = wh[lane][nc * SW + j];    // stride 101 -> 2-way max
#pragma unroll
            for (int t = 0; t < CB_R; ++t) {
                const float* mch = mbuf + (wsu * CB_R + t) * CROW + nc * SWP; // broadcast
#pragma unroll
                for (int j = 0; j < SW; ++j)
                    v[t] = fmaf(wr[j], mch[j], v[t]);   // n ascending overall
            }
        }
#pragma unroll
        for (int t = 0; t < CB_R; ++t)
            Fo[(size_t)(c0w + cb + t) * HW_SZ] = v[t];  // coalesced per c
    }
}

// -------------------------------------------------------------------------
extern "C" void kernel_launch(void* const* d_in, const int* in_sizes, int n_in,
                              void* d_out, int out_size, void* d_ws, size_t ws_size,
                              hipStream_t stream) {
    const float* F   = (const float*)d_in[0];   // [64,768,48,48]
    const float* mem = (const float*)d_in[1];   // [100,768]
    float* Fhat = (float*)d_out;                               // 113,246,208 floats
    float* What = (float*)d_out + (size_t)64 * 768 * 48 * 48;  // 14,745,600 floats
    float* mTp  = (float*)d_ws;                                // 768*112 floats

    prep_mT<<<N_MEM, 64, 0, stream>>>(mem, mTp);
    memmod_scores<<<2304, 256, 0, stream>>>(F, mTp, What);
    memmod_recon<<<2304, 256, 0, stream>>>(What, mTp, Fhat);
}

// Round 11
// 1042.865 us; speedup vs baseline: 1.9843x; 1.0507x over previous
//
#include <hip/hip_runtime.h>
#include <math.h>

#define N_MEM 100
#define C_DIM 768
#define HW_SZ 2304            // 48*48
#define TEMP 0.07f
#define EPS_F 1e-8f
#define LAM_F 0.01f           // 1/N_MEM
#define NORM_EPS 1e-12f

#define NS   4                // n-split stripes in mTp layout (fixed)
#define SW   25               // stripe width (N_MEM/NS)
#define SWP  28               // padded stripe (112B: 16B-aligned stripes)
#define CROW (NS * SWP)       // 112 floats per c in mTp
#define ROWS 64               // rows per block
#define SCP  101              // LDS row pad: lane*101%32=lane*5 -> 2-way max
#define ZB   8                // scores c-loop batch
#define CB_R 8                // recon c-tile per stage per wave

// -------------------------------------------------------------------------
// Kernel 1: L2-normalize memory rows, store PADDED-TRANSPOSED:
// mTp[c][ns][SWP]. Same value bits as R1's mT (same reduction).
// -------------------------------------------------------------------------
__global__ __launch_bounds__(64) void prep_mT(const float* __restrict__ mem,
                                              float* __restrict__ mTp) {
#pragma clang fp contract(off)
    const int n = blockIdx.x;        // 0..99
    const int lane = threadIdx.x;    // 0..63
    const float* row = mem + n * C_DIM;

    float ss = 0.f;
    for (int c = lane; c < C_DIM; c += 64) {
        float v = row[c];
        ss = fmaf(v, v, ss);
    }
    for (int off = 32; off > 0; off >>= 1)
        ss += __shfl_down(ss, off);
    float norm = sqrtf(__shfl(ss, 0));
    float inv = 1.0f / fmaxf(norm, NORM_EPS);

    const int nsI = n / SW, j = n % SW;
    for (int c = lane; c < C_DIM; c += 64)
        mTp[(size_t)c * CROW + nsI * SWP + j] = row[c] * inv;
}

// -------------------------------------------------------------------------
// FUSED kernel: scores -> softmax -> shrinkage -> w_hat -> reconstruction.
// R11 rationale: standalone scores saturates the SMEM pipe (s_load chains)
// with the LDS pipe idle; standalone recon saturates LDS with SMEM idle.
// Fused, co-resident blocks at different phases keep BOTH pipes busy, and
// recon's What re-read + wh re-staging vanish (wh overwrites the consumed
// scores in the sc buffer).
//
// NUMERICS: scores phase = R10 scores verbatim (sequential c, fmaf, s_load);
// softmax scans verbatim; wh bits written to LDS = the exact expression
// written to What; recon phase = R10 recon verbatim with wr read from sc
// (same values, same nc/j ascending n-order). absmax has been exactly
// 0.004943848 in every passing round; expect the same bits here.
// LDS: sc 25856B + mbuf 14336B = 40192B -> 4 blocks/CU (16 waves/CU).
// -------------------------------------------------------------------------
__global__ __launch_bounds__(256) void memmod_fused(const float* __restrict__ F,
                                                    const float* __restrict__ mTp,
                                                    float* __restrict__ Fhat,
                                                    float* __restrict__ What) {
#pragma clang fp contract(off)
    __shared__ float sc[ROWS][SCP];              // scores, then w_hat
    __shared__ float mbuf[NS * CB_R * CROW];     // recon m chunk

    const int tid  = threadIdx.x;
    const int lane = tid & 63;
    const int ws   = tid >> 6;
    const int wsu  = __builtin_amdgcn_readfirstlane(ws);   // force SGPR addr
    const int blk  = blockIdx.x;                 // 0..2303
    const int b    = blk / 36;                   // 36 blocks per image
    const int hw   = (blk % 36) * 64 + lane;     // 0..2303
    const int rowg = b * HW_SZ + hw;             // global row id
    const size_t plane = (size_t)b * C_DIM * HW_SZ + hw;

    float acc[SW];
#pragma unroll
    for (int j = 0; j < SW; ++j) acc[j] = 0.f;
    float ss = 0.f;

    // ---- scores: batched z loads, sequential-c FMA chains, s_load m ----
    const float* Fp = F + plane;
    for (int c0 = 0; c0 < C_DIM; c0 += ZB) {
        float zb[ZB];                            // static indices -> VGPRs
#pragma unroll
        for (int u = 0; u < ZB; ++u)
            zb[u] = Fp[(size_t)(c0 + u) * HW_SZ];    // 8 coalesced loads in flight
#pragma unroll
        for (int u = 0; u < ZB; ++u) {
            const float zc = zb[u];
            ss = fmaf(zc, zc, ss);
            const float* mch = mTp + (size_t)(c0 + u) * CROW + wsu * SWP;  // s_load
#pragma unroll
            for (int j = 0; j < SW; ++j)
                acc[j] = fmaf(zc, mch[j], acc[j]);
        }
    }

    // ---- stage scores to LDS (read-only during softmax scans) ----
#pragma unroll
    for (int j = 0; j < SW; ++j)
        sc[lane][wsu * SW + j] = acc[j];
    __syncthreads();

    // ---- softmax + shrinkage: R1's exact op sequence, n = 0..99 ----
    const float scale = 1.0f / (fmaxf(sqrtf(ss), NORM_EPS) * TEMP);
    float mx = -INFINITY;
    for (int n = 0; n < N_MEM; ++n)
        mx = fmaxf(mx, sc[lane][n] * scale);
    float sum = 0.f;
    for (int n = 0; n < N_MEM; ++n)
        sum += expf(sc[lane][n] * scale - mx);
    float s2 = 0.f;
    for (int n = 0; n < N_MEM; ++n) {
        const float e = expf(sc[lane][n] * scale - mx);   // same bits as pass 2
        const float w = e / sum;
        const float d = w - LAM_F;
        s2 += (d > 0.f ? d : 0.f) * w / (fabsf(d) + EPS_F);
    }
    const float s2c = fmaxf(s2, EPS_F);

    // ---- all waves done reading scores; overwrite sc with w_hat ----
    __syncthreads();

    // own stripe: recompute wh from registers (same bits), emit to HBM + LDS
    float* wout = What + (size_t)rowg * N_MEM + wsu * SW;
#pragma unroll
    for (int j = 0; j < SW; ++j) {
        const float e = expf(acc[j] * scale - mx);
        const float w = e / sum;
        const float d = w - LAM_F;
        const float wh = (d > 0.f ? d : 0.f) * w / (fabsf(d) + EPS_F);
        const float whn = wh / s2c;
        wout[j] = whn;                           // output w_hat_spatial
        sc[lane][wsu * SW + j] = whn;            // recon operand (same bits)
    }

    // ---- reconstruction: Fhat[b][c][hw] = sum_n wh[row][n]*m[n][c] ----
    float* Fo = Fhat + plane;
    const int c0w = wsu * (C_DIM / NS);          // 192-wide c-stripe

    for (int cb = 0; cb < C_DIM / NS; cb += CB_R) {
        __syncthreads();                         // wh visible / prior chunk consumed
        {   // stage 4 c-regions x CB_R c's x 112 floats = 896 float4
            float4* dst4 = reinterpret_cast<float4*>(mbuf);
            for (int i = tid; i < NS * CB_R * CROW / 4; i += 256) {
                const int s   = i / (CB_R * CROW / 4);
                const int rem = i % (CB_R * CROW / 4);
                const float4* src4 = reinterpret_cast<const float4*>(
                    mTp + (size_t)(s * (C_DIM / NS) + cb) * CROW);
                dst4[i] = src4[rem];
            }
        }
        __syncthreads();

        float v[CB_R];
#pragma unroll
        for (int t = 0; t < CB_R; ++t) v[t] = 0.f;

#pragma unroll
        for (int nc = 0; nc < NS; ++nc) {
            float wr[SW];
#pragma unroll
            for (int j = 0; j < SW; ++j)
                wr[j] = sc[lane][nc * SW + j];    // w_hat, stride 101 -> 2-way max
#pragma unroll
            for (int t = 0; t < CB_R; ++t) {
                const float* mch = mbuf + (wsu * CB_R + t) * CROW + nc * SWP; // broadcast
#pragma unroll
                for (int j = 0; j < SW; ++j)
                    v[t] = fmaf(wr[j], mch[j], v[t]);   // n ascending overall
            }
        }
#pragma unroll
        for (int t = 0; t < CB_R; ++t)
            Fo[(size_t)(c0w + cb + t) * HW_SZ] = v[t];  // coalesced per c
    }
}

// -------------------------------------------------------------------------
extern "C" void kernel_launch(void* const* d_in, const int* in_sizes, int n_in,
                              void* d_out, int out_size, void* d_ws, size_t ws_size,
                              hipStream_t stream) {
    const float* F   = (const float*)d_in[0];   // [64,768,48,48]
    const float* mem = (const float*)d_in[1];   // [100,768]
    float* Fhat = (float*)d_out;                               // 113,246,208 floats
    float* What = (float*)d_out + (size_t)64 * 768 * 48 * 48;  // 14,745,600 floats
    float* mTp  = (float*)d_ws;                                // 768*112 floats

    prep_mT<<<N_MEM, 64, 0, stream>>>(mem, mTp);
    memmod_fused<<<2304, 256, 0, stream>>>(F, mTp, Fhat, What);
}